// Round 11
// baseline (200.584 us; speedup 1.0000x reference)
//
#include <hip/hip_runtime.h>

constexpr int DIN  = 128;
constexpr int DOUT = 128;
constexpr float EPS_SCALE = 1e-7f;

typedef __attribute__((ext_vector_type(8))) short bf16x8;
typedef __attribute__((ext_vector_type(4))) float f32x4;

__device__ __forceinline__ float lrelu(float x) { return fmaxf(x, 0.01f * x); }

__device__ __forceinline__ unsigned short f2bf(float x) {
    unsigned u = __float_as_uint(x);
    unsigned r = (u + 0x7FFFu + ((u >> 16) & 1u)) >> 16;   // RNE
    return (unsigned short)r;
}
__device__ __forceinline__ float bf2f(unsigned short h) {
    return __uint_as_float(((unsigned)h) << 16);
}

// ---------------------------------------------------------------------------
// 1) Fused prep: hist(dst) | feat fp32->bf16 | pack W frags + bias | pos4.
// ---------------------------------------------------------------------------
__global__ __launch_bounds__(256) void prep_kernel(
    const int* __restrict__ dst, int* __restrict__ hist, int E, int eb,
    const float* __restrict__ feat, unsigned short* __restrict__ featbf,
    int total8, int cb,
    const float* __restrict__ Wself, const float* __restrict__ Wneigh,
    const float* __restrict__ b_self, const float* __restrict__ b_neigh,
    const float* __restrict__ bias,
    unsigned short* __restrict__ bfrag, float* __restrict__ bb, int pb,
    const float* __restrict__ pos, float4* __restrict__ pos4, int N)
{
    int b = blockIdx.x;
    int tid = threadIdx.x;
    if (b < eb) {
        int e = b * 256 + tid;
        if (e < E) atomicAdd(&hist[dst[e]], 1);
    } else if (b < eb + cb) {
        int i = (b - eb) * 256 + tid;          // handles 8 floats
        if (i < total8) {
            float4 v0 = *(const float4*)(feat + (size_t)i * 8);
            float4 v1 = *(const float4*)(feat + (size_t)i * 8 + 4);
            bf16x8 o;
            o[0] = (short)f2bf(v0.x); o[1] = (short)f2bf(v0.y);
            o[2] = (short)f2bf(v0.z); o[3] = (short)f2bf(v0.w);
            o[4] = (short)f2bf(v1.x); o[5] = (short)f2bf(v1.y);
            o[6] = (short)f2bf(v1.z); o[7] = (short)f2bf(v1.w);
            *(bf16x8*)(featbf + (size_t)i * 8) = o;
        }
    } else if (b < eb + cb + pb) {
        int idx = (b - eb - cb) * 256 + tid;   // 0..32767
        if (idx < 32768) {
            int j = idx & 7;
            int l = (idx >> 3) & 63;
            int f = (idx >> 9) & 7;
            int s = (idx >> 12) & 7;
            int k = s * 32 + ((l >> 4) << 3) + j;
            int c = f * 16 + (l & 15);
            float v = (k < 128) ? Wself[c * 128 + k] : Wneigh[c * 128 + (k - 128)];
            bfrag[idx] = f2bf(v);
        }
        if (idx < 128) bb[idx] = b_self[idx] + b_neigh[idx] + bias[idx];
    } else {
        int i = (b - eb - cb - pb) * 256 + tid;
        if (i < N) {
            pos4[i] = make_float4(pos[i * 3 + 0], pos[i * 3 + 1],
                                  pos[i * 3 + 2], 0.0f);
        }
    }
}

// ---------------------------------------------------------------------------
// 2) Single-kernel exclusive scan -> rowptr[0..N], rowptr[N]=E.
// ---------------------------------------------------------------------------
__global__ __launch_bounds__(256) void scan_kernel(
    const int* __restrict__ hist, int* __restrict__ rowptr, int N, int E)
{
    __shared__ int wred[4];
    __shared__ int wsum[4];
    int tid = threadIdx.x, wave = tid >> 6, lane = tid & 63;

    int limit = blockIdx.x << 10;
    int acc = 0;
    for (int i = tid * 4; i < limit; i += 1024) {
        int4 h = *(const int4*)(hist + i);
        acc += h.x + h.y + h.z + h.w;
    }
#pragma unroll
    for (int off = 1; off < 64; off <<= 1) acc += __shfl_xor(acc, off, 64);
    if (lane == 0) wred[wave] = acc;
    __syncthreads();
    int base_s = wred[0] + wred[1] + wred[2] + wred[3];

    int idx = blockIdx.x * 1024 + tid * 4;
    int4 h = make_int4(0, 0, 0, 0);
    if (idx < N) h = *(const int4*)(hist + idx);
    int s = h.x + h.y + h.z + h.w;
    int x = s;
#pragma unroll
    for (int off = 1; off < 64; off <<= 1) {
        int v = __shfl_up(x, off, 64);
        if (lane >= off) x += v;
    }
    if (lane == 63) wsum[wave] = x;
    __syncthreads();
    int wb = 0;
#pragma unroll
    for (int w = 0; w < 4; ++w) if (w < wave) wb += wsum[w];
    int base = base_s + wb + (x - s);
    if (idx < N) {
        rowptr[idx + 0] = base;
        rowptr[idx + 1] = base + h.x;
        rowptr[idx + 2] = base + h.x + h.y;
        rowptr[idx + 3] = base + h.x + h.y + h.z;
    }
    if (blockIdx.x == 0 && tid == 0) rowptr[N] = E;
}

// ---------------------------------------------------------------------------
// 3) Scatter: per-edge spatial coeff + src id (float4), CSR order.
// ---------------------------------------------------------------------------
__global__ __launch_bounds__(256) void scatter_kernel(
    const int* __restrict__ dst, const int* __restrict__ src,
    const float4* __restrict__ pos4,
    const int* __restrict__ rowptr, int* __restrict__ cur,
    float4* __restrict__ ecoef, int E)
{
    int e = blockIdx.x * blockDim.x + threadIdx.x;
    if (e < E) {
        int d = dst[e];
        int s = src[e];
        float4 pd = pos4[d];
        float4 ps = pos4[s];
        float r0 = pd.x - ps.x;
        float r1 = pd.y - ps.y;
        float r2 = pd.z - ps.z;
        float inv = 1.0f / (sqrtf(r0 * r0 + r1 * r1 + r2 * r2) + EPS_SCALE);
        int p = atomicAdd(&cur[d], 1);
        ecoef[rowptr[d] + p] = make_float4((r0 + 1.0f) * inv, (r1 + 1.0f) * inv,
                                           (r2 + 1.0f) * inv, __int_as_float(s));
    }
}

// ---------------------------------------------------------------------------
// 4) FUSED gather + node GEMM.
//    Block = 4 waves, 64 rows. Wave w owns rows r0+w*16 .. +15:
//      phase A: for each of its 16 rows, r8-form gather (2x-unrolled quarter
//               loop, 8 load-chains in flight) -> h_mean bf16 row stashed in
//               wave-private LDS [16][128] with XOR swizzle (row&7)<<4.
//      phase B: MFMA over K=256: s=0..3 A-frags from featbf (global),
//               s=4..7 from the LDS hm tile; epilogue + lrelu -> out.
//    No __syncthreads: LDS region is wave-private (one lgkmcnt between
//    phases). Waves drift through phases independently -> MFMA/VALU overlap.
// ---------------------------------------------------------------------------
#define EDGE_FMA(QC, F)                                                          \
    do {                                                                         \
        a0 = fmaf(lrelu(fmaf(QC.x, w0.x, fmaf(QC.y, w0.y, fmaf(QC.z, w0.z, b0.x)))), \
                  bf2f((unsigned short)F[0]), a0);                               \
        a1 = fmaf(lrelu(fmaf(QC.x, w0.w, fmaf(QC.y, w1.x, fmaf(QC.z, w1.y, b0.y)))), \
                  bf2f((unsigned short)F[1]), a1);                               \
        a2 = fmaf(lrelu(fmaf(QC.x, w1.z, fmaf(QC.y, w1.w, fmaf(QC.z, w2.x, b0.z)))), \
                  bf2f((unsigned short)F[2]), a2);                               \
        a3 = fmaf(lrelu(fmaf(QC.x, w2.y, fmaf(QC.y, w2.z, fmaf(QC.z, w2.w, b0.w)))), \
                  bf2f((unsigned short)F[3]), a3);                               \
        a4 = fmaf(lrelu(fmaf(QC.x, w3.x, fmaf(QC.y, w3.y, fmaf(QC.z, w3.z, b1.x)))), \
                  bf2f((unsigned short)F[4]), a4);                               \
        a5 = fmaf(lrelu(fmaf(QC.x, w3.w, fmaf(QC.y, w4.x, fmaf(QC.z, w4.y, b1.y)))), \
                  bf2f((unsigned short)F[5]), a5);                               \
        a6 = fmaf(lrelu(fmaf(QC.x, w4.z, fmaf(QC.y, w4.w, fmaf(QC.z, w5.x, b1.z)))), \
                  bf2f((unsigned short)F[6]), a6);                               \
        a7 = fmaf(lrelu(fmaf(QC.x, w5.y, fmaf(QC.y, w5.z, fmaf(QC.z, w5.w, b1.w)))), \
                  bf2f((unsigned short)F[7]), a7);                               \
    } while (0)

__global__ __launch_bounds__(256) void gather_node_kernel(
    const unsigned short* __restrict__ featbf,
    const float4* __restrict__ ecoef,
    const int*   __restrict__ rowptr,
    const float* __restrict__ Wsp,   // [128][3]
    const float* __restrict__ bsp,   // [128]
    const unsigned short* __restrict__ bfrag,
    const float* __restrict__ bb,
    float* __restrict__ out, int N)
{
    __shared__ unsigned short hlds[4][16][128];   // 16 KB, wave-private tiles

    int tid  = threadIdx.x;
    int wv   = tid >> 6;
    int lane = tid & 63;
    int q    = lane >> 4;
    int sl   = lane & 15;
    int d    = sl * 8;
    int r0   = blockIdx.x * 64 + wv * 16;

    const float4* wp = (const float4*)(Wsp + d * 3);
    float4 w0 = wp[0], w1 = wp[1], w2 = wp[2];
    float4 w3 = wp[3], w4 = wp[4], w5 = wp[5];
    float4 b0 = *(const float4*)(bsp + d);
    float4 b1 = *(const float4*)(bsp + d + 4);

    const unsigned short* fb = featbf + d;
    char* lbase = (char*)&hlds[wv][0][0];

    // ---- phase A: gather h_mean for rows r0..r0+15 into LDS ----
    for (int idx = 0; idx < 16; ++idx) {
        int v = r0 + idx;
        if (v >= N) break;
        int start = rowptr[v];
        int end   = rowptr[v + 1];

        float a0 = 0.f, a1 = 0.f, a2 = 0.f, a3 = 0.f;
        float a4 = 0.f, a5 = 0.f, a6 = 0.f, a7 = 0.f;

        int i = start + q;
        for (; i + 4 < end; i += 8) {
            float4 qcA = ecoef[i];
            float4 qcB = ecoef[i + 4];
            bf16x8 fA = *(const bf16x8*)(fb + (size_t)__float_as_int(qcA.w) * DIN);
            bf16x8 fB = *(const bf16x8*)(fb + (size_t)__float_as_int(qcB.w) * DIN);
            EDGE_FMA(qcA, fA);
            EDGE_FMA(qcB, fB);
        }
        if (i < end) {
            float4 qcA = ecoef[i];
            bf16x8 fA = *(const bf16x8*)(fb + (size_t)__float_as_int(qcA.w) * DIN);
            EDGE_FMA(qcA, fA);
        }

        a0 += __shfl_xor(a0, 16); a0 += __shfl_xor(a0, 32);
        a1 += __shfl_xor(a1, 16); a1 += __shfl_xor(a1, 32);
        a2 += __shfl_xor(a2, 16); a2 += __shfl_xor(a2, 32);
        a3 += __shfl_xor(a3, 16); a3 += __shfl_xor(a3, 32);
        a4 += __shfl_xor(a4, 16); a4 += __shfl_xor(a4, 32);
        a5 += __shfl_xor(a5, 16); a5 += __shfl_xor(a5, 32);
        a6 += __shfl_xor(a6, 16); a6 += __shfl_xor(a6, 32);
        a7 += __shfl_xor(a7, 16); a7 += __shfl_xor(a7, 32);

        if (q == 0) {
            float invd = 1.0f / fmaxf((float)(end - start), 1.0f);
            bf16x8 o;
            o[0] = (short)f2bf(a0 * invd); o[1] = (short)f2bf(a1 * invd);
            o[2] = (short)f2bf(a2 * invd); o[3] = (short)f2bf(a3 * invd);
            o[4] = (short)f2bf(a4 * invd); o[5] = (short)f2bf(a5 * invd);
            o[6] = (short)f2bf(a6 * invd); o[7] = (short)f2bf(a7 * invd);
            // swizzled wave-private stash: row idx, bytes (sl*16)^((idx&7)<<4)
            *(bf16x8*)(lbase + idx * 256 + ((sl * 16) ^ ((idx & 7) << 4))) = o;
        }
    }

    // wave-private LDS: only need DS-queue drain, no barrier
    asm volatile("s_waitcnt lgkmcnt(0)" ::: "memory");

    // ---- phase B: MFMA over K=256 for rows r0..r0+15 ----
    int row  = r0 + sl;
    bool rowok = row < N;
    int kb = q << 3;                 // k sub-offset (elements) within 32-step

    f32x4 acc[8];
#pragma unroll
    for (int f = 0; f < 8; ++f) acc[f] = (f32x4)0.0f;

#pragma unroll
    for (int s = 0; s < 8; ++s) {
        bf16x8 a;
        if (s < 4) {
            a = (bf16x8)(short)0;
            if (rowok)
                a = *(const bf16x8*)(featbf + (size_t)row * DIN + s * 32 + kb);
        } else {
            int kb2 = (s & 3) * 64 + q * 16;      // byte offset of k-slice
            a = *(const bf16x8*)(lbase + sl * 256 + (kb2 ^ ((sl & 7) << 4)));
        }
#pragma unroll
        for (int f = 0; f < 8; ++f) {
            bf16x8 b = *(const bf16x8*)(bfrag + ((((s * 8 + f) * 64) + lane) * 8));
            acc[f] = __builtin_amdgcn_mfma_f32_16x16x32_bf16(a, b, acc[f], 0, 0, 0);
        }
    }

    int crow = r0 + (q << 2);
    int col  = sl;
#pragma unroll
    for (int f = 0; f < 8; ++f) {
        int c = f * 16 + col;
        float bbv = bb[c];
#pragma unroll
        for (int r = 0; r < 4; ++r) {
            int rr = crow + r;
            if (rr < N) out[(size_t)rr * DOUT + c] = lrelu(acc[f][r] + bbv);
        }
    }
}

// ---------------------------------------------------------------------------
extern "C" void kernel_launch(void* const* d_in, const int* in_sizes, int n_in,
                              void* d_out, int out_size, void* d_ws, size_t ws_size,
                              hipStream_t stream)
{
    const float* feat    = (const float*)d_in[0];
    const float* pos     = (const float*)d_in[1];
    const int*   src     = (const int*)  d_in[2];
    const int*   dst     = (const int*)  d_in[3];
    const float* Wsp     = (const float*)d_in[4];
    const float* bsp     = (const float*)d_in[5];
    const float* Wneigh  = (const float*)d_in[6];
    const float* b_neigh = (const float*)d_in[7];
    const float* Wself   = (const float*)d_in[8];
    const float* b_self  = (const float*)d_in[9];
    const float* bias    = (const float*)d_in[10];

    int N = in_sizes[0] / DIN;
    int E = in_sizes[2];
    int nb = (N + 1023) / 1024;   // scan blocks

    // Workspace layout (all 16B aligned):
    // featbf [N*128 u16] | ecoef [E f4] | pos4 [N f4] | bfrag [32768 u16]
    // | bb [128 f32] | hist [N] | cur [N] | rowptr [N+4]
    char* p = (char*)d_ws;
    unsigned short* featbf = (unsigned short*)p; p += (size_t)N * DIN * 2;
    float4* ecoef          = (float4*)p;         p += (size_t)E * 16;
    float4* pos4           = (float4*)p;         p += (size_t)N * 16;
    unsigned short* bfrag  = (unsigned short*)p; p += 32768 * 2;
    float* bb              = (float*)p;          p += 128 * 4;
    int* hist              = (int*)p;            p += (size_t)N * 4;
    int* cur               = (int*)p;            p += (size_t)N * 4;
    int* rowptr            = (int*)p;

    // zero hist + cur (adjacent)
    hipMemsetAsync(hist, 0, (size_t)2 * N * sizeof(int), stream);

    int eb = (E + 255) / 256;            // hist blocks
    int cb = (N * 16 + 255) / 256;       // convert blocks (N*128/8 threads)
    int pb = 129;                        // pack blocks
    int qb = (N + 255) / 256;            // pos4 blocks
    prep_kernel<<<eb + cb + pb + qb, 256, 0, stream>>>(
        dst, hist, E, eb, feat, featbf, N * 16, cb,
        Wself, Wneigh, b_self, b_neigh, bias, bfrag, bb, pb, pos, pos4, N);

    scan_kernel<<<nb, 256, 0, stream>>>(hist, rowptr, N, E);

    scatter_kernel<<<eb, 256, 0, stream>>>(dst, src, pos4, rowptr, cur, ecoef, E);

    gather_node_kernel<<<(N + 63) / 64, 256, 0, stream>>>(
        featbf, ecoef, rowptr, Wsp, bsp, bfrag, bb, (float*)d_out, N);
}

// Round 12
// 158.322 us; speedup vs baseline: 1.2669x; 1.2669x over previous
//
#include <hip/hip_runtime.h>

constexpr int DIN  = 128;
constexpr int DOUT = 128;
constexpr float EPS_SCALE = 1e-7f;

typedef __attribute__((ext_vector_type(8))) short bf16x8;
typedef __attribute__((ext_vector_type(4))) float f32x4;

__device__ __forceinline__ float lrelu(float x) { return fmaxf(x, 0.01f * x); }

__device__ __forceinline__ unsigned short f2bf(float x) {
    unsigned u = __float_as_uint(x);
    unsigned r = (u + 0x7FFFu + ((u >> 16) & 1u)) >> 16;   // RNE
    return (unsigned short)r;
}
__device__ __forceinline__ float bf2f(unsigned short h) {
    return __uint_as_float(((unsigned)h) << 16);
}

// ---------------------------------------------------------------------------
// 1) Fused prep: hist(dst) | feat fp32->bf16 | pack W frags + combined bias.
// ---------------------------------------------------------------------------
__global__ __launch_bounds__(256) void prep_kernel(
    const int* __restrict__ dst, int* __restrict__ hist, int E, int eb,
    const float* __restrict__ feat, unsigned short* __restrict__ featbf,
    int total8, int cb,
    const float* __restrict__ Wself, const float* __restrict__ Wneigh,
    const float* __restrict__ b_self, const float* __restrict__ b_neigh,
    const float* __restrict__ bias,
    unsigned short* __restrict__ bfrag, float* __restrict__ bb)
{
    int b = blockIdx.x;
    int tid = threadIdx.x;
    if (b < eb) {
        int e = b * 256 + tid;
        if (e < E) atomicAdd(&hist[dst[e]], 1);
    } else if (b < eb + cb) {
        int i = (b - eb) * 256 + tid;          // handles 8 floats
        if (i < total8) {
            float4 v0 = *(const float4*)(feat + (size_t)i * 8);
            float4 v1 = *(const float4*)(feat + (size_t)i * 8 + 4);
            bf16x8 o;
            o[0] = (short)f2bf(v0.x); o[1] = (short)f2bf(v0.y);
            o[2] = (short)f2bf(v0.z); o[3] = (short)f2bf(v0.w);
            o[4] = (short)f2bf(v1.x); o[5] = (short)f2bf(v1.y);
            o[6] = (short)f2bf(v1.z); o[7] = (short)f2bf(v1.w);
            *(bf16x8*)(featbf + (size_t)i * 8) = o;
        }
    } else {
        int idx = (b - eb - cb) * 256 + tid;   // 0..32767
        if (idx < 32768) {
            int j = idx & 7;
            int l = (idx >> 3) & 63;
            int f = (idx >> 9) & 7;
            int s = (idx >> 12) & 7;
            int k = s * 32 + ((l >> 4) << 3) + j;
            int c = f * 16 + (l & 15);
            float v = (k < 128) ? Wself[c * 128 + k] : Wneigh[c * 128 + (k - 128)];
            bfrag[idx] = f2bf(v);
        }
        if (idx < 128) bb[idx] = b_self[idx] + b_neigh[idx] + bias[idx];
    }
}

// ---------------------------------------------------------------------------
// 2a) Per-block partial sums over 1024-elem chunks
// ---------------------------------------------------------------------------
__global__ __launch_bounds__(256) void scan_part1(
    const int* __restrict__ hist, int* __restrict__ bsum, int N)
{
    __shared__ int wsum[4];
    int tid = threadIdx.x, wave = tid >> 6, lane = tid & 63;
    int idx = blockIdx.x * 1024 + tid * 4;
    int4 h = make_int4(0, 0, 0, 0);
    if (idx < N) h = *(const int4*)(hist + idx);
    int s = h.x + h.y + h.z + h.w;
#pragma unroll
    for (int off = 1; off < 64; off <<= 1) s += __shfl_xor(s, off, 64);
    if (lane == 0) wsum[wave] = s;
    __syncthreads();
    if (tid == 0) bsum[blockIdx.x] = wsum[0] + wsum[1] + wsum[2] + wsum[3];
}

// ---------------------------------------------------------------------------
// 2b) Exclusive scan of <=64 block partials; rowptr[N] = E
// ---------------------------------------------------------------------------
__global__ __launch_bounds__(64) void scan_part2(
    const int* __restrict__ bsum, int* __restrict__ bbase, int nb,
    int* __restrict__ rowptr, int N, int E)
{
    int lane = threadIdx.x;
    int x = (lane < nb) ? bsum[lane] : 0;
    int orig = x;
#pragma unroll
    for (int off = 1; off < 64; off <<= 1) {
        int v = __shfl_up(x, off, 64);
        if (lane >= off) x += v;
    }
    if (lane < nb) bbase[lane] = x - orig;
    if (lane == 0) rowptr[N] = E;
}

// ---------------------------------------------------------------------------
// 2c) In-block exclusive scan + block base -> rowptr[0..N-1]
// ---------------------------------------------------------------------------
__global__ __launch_bounds__(256) void scan_part3(
    const int* __restrict__ hist, const int* __restrict__ bbase,
    int* __restrict__ rowptr, int N)
{
    __shared__ int wsum[4];
    int tid = threadIdx.x, wave = tid >> 6, lane = tid & 63;
    int idx = blockIdx.x * 1024 + tid * 4;
    int4 h = make_int4(0, 0, 0, 0);
    if (idx < N) h = *(const int4*)(hist + idx);
    int s = h.x + h.y + h.z + h.w;
    int x = s;
#pragma unroll
    for (int off = 1; off < 64; off <<= 1) {
        int v = __shfl_up(x, off, 64);
        if (lane >= off) x += v;
    }
    if (lane == 63) wsum[wave] = x;
    __syncthreads();
    int wb = 0;
#pragma unroll
    for (int w = 0; w < 4; ++w) if (w < wave) wb += wsum[w];
    int base = bbase[blockIdx.x] + wb + (x - s);
    if (idx < N) {
        rowptr[idx + 0] = base;
        rowptr[idx + 1] = base + h.x;
        rowptr[idx + 2] = base + h.x + h.y;
        rowptr[idx + 3] = base + h.x + h.y + h.z;
    }
}

// ---------------------------------------------------------------------------
// 3) Scatter: compute per-edge spatial coeff + pack src id, in CSR order.
// ---------------------------------------------------------------------------
__global__ __launch_bounds__(256) void scatter_kernel(
    const int* __restrict__ dst, const int* __restrict__ src,
    const float* __restrict__ pos,
    const int* __restrict__ rowptr, int* __restrict__ cur,
    float4* __restrict__ ecoef, int E)
{
    int e = blockIdx.x * blockDim.x + threadIdx.x;
    if (e < E) {
        int d = dst[e];
        int s = src[e];
        float r0 = pos[d * 3 + 0] - pos[s * 3 + 0];
        float r1 = pos[d * 3 + 1] - pos[s * 3 + 1];
        float r2 = pos[d * 3 + 2] - pos[s * 3 + 2];
        float inv = 1.0f / (sqrtf(r0 * r0 + r1 * r1 + r2 * r2) + EPS_SCALE);
        int p = atomicAdd(&cur[d], 1);
        ecoef[rowptr[d] + p] = make_float4((r0 + 1.0f) * inv, (r1 + 1.0f) * inv,
                                           (r2 + 1.0f) * inv, __int_as_float(s));
    }
}

// ---------------------------------------------------------------------------
// 4) Gather: persistent waves, 2x-unrolled quarter loop -> 8 independent
//    edge load-chains in flight per wave. Wave per node (grid-stride);
//    quarter q owns edges start+q (step 4); sl owns dims sl*8..sl*8+7.
// ---------------------------------------------------------------------------
#define EDGE_FMA(QC, F)                                                          \
    do {                                                                         \
        a0 = fmaf(lrelu(fmaf(QC.x, w0.x, fmaf(QC.y, w0.y, fmaf(QC.z, w0.z, b0.x)))), \
                  bf2f((unsigned short)F[0]), a0);                               \
        a1 = fmaf(lrelu(fmaf(QC.x, w0.w, fmaf(QC.y, w1.x, fmaf(QC.z, w1.y, b0.y)))), \
                  bf2f((unsigned short)F[1]), a1);                               \
        a2 = fmaf(lrelu(fmaf(QC.x, w1.z, fmaf(QC.y, w1.w, fmaf(QC.z, w2.x, b0.z)))), \
                  bf2f((unsigned short)F[2]), a2);                               \
        a3 = fmaf(lrelu(fmaf(QC.x, w2.y, fmaf(QC.y, w2.z, fmaf(QC.z, w2.w, b0.w)))), \
                  bf2f((unsigned short)F[3]), a3);                               \
        a4 = fmaf(lrelu(fmaf(QC.x, w3.x, fmaf(QC.y, w3.y, fmaf(QC.z, w3.z, b1.x)))), \
                  bf2f((unsigned short)F[4]), a4);                               \
        a5 = fmaf(lrelu(fmaf(QC.x, w3.w, fmaf(QC.y, w4.x, fmaf(QC.z, w4.y, b1.y)))), \
                  bf2f((unsigned short)F[5]), a5);                               \
        a6 = fmaf(lrelu(fmaf(QC.x, w4.z, fmaf(QC.y, w4.w, fmaf(QC.z, w5.x, b1.z)))), \
                  bf2f((unsigned short)F[6]), a6);                               \
        a7 = fmaf(lrelu(fmaf(QC.x, w5.y, fmaf(QC.y, w5.z, fmaf(QC.z, w5.w, b1.w)))), \
                  bf2f((unsigned short)F[7]), a7);                               \
    } while (0)

__global__ __launch_bounds__(256) void gather_kernel(
    const unsigned short* __restrict__ featbf,
    const float4* __restrict__ ecoef,
    const int*   __restrict__ rowptr,
    const float* __restrict__ Wsp,   // [128][3]
    const float* __restrict__ bsp,   // [128]
    unsigned short* __restrict__ hmbf,  // [N][128]
    int N, int nwaves)
{
    int gw   = (blockIdx.x * 256 + threadIdx.x) >> 6;
    int lane = threadIdx.x & 63;
    int q    = lane >> 4;
    int sl   = lane & 15;
    int d    = sl * 8;

    const float4* wp = (const float4*)(Wsp + d * 3);
    float4 w0 = wp[0], w1 = wp[1], w2 = wp[2];
    float4 w3 = wp[3], w4 = wp[4], w5 = wp[5];
    float4 b0 = *(const float4*)(bsp + d);
    float4 b1 = *(const float4*)(bsp + d + 4);

    const unsigned short* fb = featbf + d;

    for (int v = gw; v < N; v += nwaves) {
        int start = rowptr[v];
        int end   = rowptr[v + 1];

        float a0 = 0.f, a1 = 0.f, a2 = 0.f, a3 = 0.f;
        float a4 = 0.f, a5 = 0.f, a6 = 0.f, a7 = 0.f;

        int i = start + q;
        // Pairs: edges i and i+4, all loads issued before compute.
        for (; i + 4 < end; i += 8) {
            float4 qcA = ecoef[i];
            float4 qcB = ecoef[i + 4];
            bf16x8 fA = *(const bf16x8*)(fb + (size_t)__float_as_int(qcA.w) * DIN);
            bf16x8 fB = *(const bf16x8*)(fb + (size_t)__float_as_int(qcB.w) * DIN);
            EDGE_FMA(qcA, fA);
            EDGE_FMA(qcB, fB);
        }
        if (i < end) {
            float4 qcA = ecoef[i];
            bf16x8 fA = *(const bf16x8*)(fb + (size_t)__float_as_int(qcA.w) * DIN);
            EDGE_FMA(qcA, fA);
        }

        a0 += __shfl_xor(a0, 16); a0 += __shfl_xor(a0, 32);
        a1 += __shfl_xor(a1, 16); a1 += __shfl_xor(a1, 32);
        a2 += __shfl_xor(a2, 16); a2 += __shfl_xor(a2, 32);
        a3 += __shfl_xor(a3, 16); a3 += __shfl_xor(a3, 32);
        a4 += __shfl_xor(a4, 16); a4 += __shfl_xor(a4, 32);
        a5 += __shfl_xor(a5, 16); a5 += __shfl_xor(a5, 32);
        a6 += __shfl_xor(a6, 16); a6 += __shfl_xor(a6, 32);
        a7 += __shfl_xor(a7, 16); a7 += __shfl_xor(a7, 32);

        if (q == 0) {
            float invd = 1.0f / fmaxf((float)(end - start), 1.0f);
            bf16x8 o;
            o[0] = (short)f2bf(a0 * invd); o[1] = (short)f2bf(a1 * invd);
            o[2] = (short)f2bf(a2 * invd); o[3] = (short)f2bf(a3 * invd);
            o[4] = (short)f2bf(a4 * invd); o[5] = (short)f2bf(a5 * invd);
            o[6] = (short)f2bf(a6 * invd); o[7] = (short)f2bf(a7 * invd);
            *(bf16x8*)(hmbf + (size_t)v * DIN + d) = o;
        }
    }
}

// ---------------------------------------------------------------------------
// 5) Node GEMM via MFMA: out = lrelu([featbf | hmbf] @ Wc^T + bb)
// ---------------------------------------------------------------------------
__global__ __launch_bounds__(256) void node_mfma_kernel(
    const unsigned short* __restrict__ featbf,
    const unsigned short* __restrict__ hmbf,
    const unsigned short* __restrict__ bfrag,
    const float* __restrict__ bb,
    float* __restrict__ out, int N)
{
    int wave = threadIdx.x >> 6;
    int lane = threadIdx.x & 63;
    int r0   = blockIdx.x * 64 + wave * 16;
    int row  = r0 + (lane & 15);
    bool rowok = row < N;
    int kb = (lane >> 4) << 3;

    f32x4 acc[8];
#pragma unroll
    for (int f = 0; f < 8; ++f) acc[f] = (f32x4)0.0f;

#pragma unroll
    for (int s = 0; s < 8; ++s) {
        bf16x8 a = (bf16x8)(short)0;
        if (rowok) {
            const unsigned short* base =
                (s < 4 ? featbf : hmbf) + (size_t)row * DIN + (s & 3) * 32 + kb;
            a = *(const bf16x8*)base;
        }
#pragma unroll
        for (int f = 0; f < 8; ++f) {
            bf16x8 b = *(const bf16x8*)(bfrag + ((((s * 8 + f) * 64) + lane) * 8));
            acc[f] = __builtin_amdgcn_mfma_f32_16x16x32_bf16(a, b, acc[f], 0, 0, 0);
        }
    }

    int crow = r0 + ((lane >> 4) << 2);
    int col  = lane & 15;
#pragma unroll
    for (int f = 0; f < 8; ++f) {
        int c = f * 16 + col;
        float bbv = bb[c];
#pragma unroll
        for (int r = 0; r < 4; ++r) {
            int rr = crow + r;
            if (rr < N) out[(size_t)rr * DOUT + c] = lrelu(acc[f][r] + bbv);
        }
    }
}

// ---------------------------------------------------------------------------
extern "C" void kernel_launch(void* const* d_in, const int* in_sizes, int n_in,
                              void* d_out, int out_size, void* d_ws, size_t ws_size,
                              hipStream_t stream)
{
    const float* feat    = (const float*)d_in[0];
    const float* pos     = (const float*)d_in[1];
    const int*   src     = (const int*)  d_in[2];
    const int*   dst     = (const int*)  d_in[3];
    const float* Wsp     = (const float*)d_in[4];
    const float* bsp     = (const float*)d_in[5];
    const float* Wneigh  = (const float*)d_in[6];
    const float* b_neigh = (const float*)d_in[7];
    const float* Wself   = (const float*)d_in[8];
    const float* b_self  = (const float*)d_in[9];
    const float* bias    = (const float*)d_in[10];

    int N = in_sizes[0] / DIN;
    int E = in_sizes[2];
    int nb = (N + 1023) / 1024;   // scan blocks (49 for N=50000; <= 64)

    // Workspace layout (all 16B aligned):
    // featbf [N*128 u16] | hmbf [N*128 u16] | ecoef [E f4] | bfrag [32768 u16]
    // | bb [128 f32] | hist [N] | cur [N] | rowptr [N+4] | bsum [64] | bbase [64]
    char* p = (char*)d_ws;
    unsigned short* featbf = (unsigned short*)p; p += (size_t)N * DIN * 2;
    unsigned short* hmbf   = (unsigned short*)p; p += (size_t)N * DIN * 2;
    float4* ecoef          = (float4*)p;         p += (size_t)E * 16;
    unsigned short* bfrag  = (unsigned short*)p; p += 32768 * 2;
    float* bb              = (float*)p;          p += 128 * 4;
    int* hist              = (int*)p;            p += (size_t)N * 4;
    int* cur               = (int*)p;            p += (size_t)N * 4;
    int* rowptr            = (int*)p;            p += (size_t)(N + 4) * 4;
    int* bsum              = (int*)p;            p += 64 * 4;
    int* bbase             = (int*)p;

    // zero hist + cur (adjacent)
    hipMemsetAsync(hist, 0, (size_t)2 * N * sizeof(int), stream);

    int eb = (E + 255) / 256;            // hist blocks
    int cb = (N * 16 + 255) / 256;       // convert blocks (N*128/8 threads)
    int pb = 129;                        // pack blocks
    prep_kernel<<<eb + cb + pb, 256, 0, stream>>>(
        dst, hist, E, eb, feat, featbf, N * 16, cb,
        Wself, Wneigh, b_self, b_neigh, bias, bfrag, bb);

    scan_part1<<<nb, 256, 0, stream>>>(hist, bsum, N);
    scan_part2<<<1, 64, 0, stream>>>(bsum, bbase, nb, rowptr, N, E);
    scan_part3<<<nb, 256, 0, stream>>>(hist, bbase, rowptr, N);

    scatter_kernel<<<eb, 256, 0, stream>>>(dst, src, pos, rowptr, cur, ecoef, E);

    int gblocks = 2048;
    gather_kernel<<<gblocks, 256, 0, stream>>>(featbf, ecoef, rowptr, Wsp, bsp,
                                               hmbf, N, gblocks * 4);

    node_mfma_kernel<<<(N + 63) / 64, 256, 0, stream>>>(featbf, hmbf, bfrag, bb,
                                                        (float*)d_out, N);
}

// Round 13
// 152.596 us; speedup vs baseline: 1.3145x; 1.0375x over previous
//
#include <hip/hip_runtime.h>

constexpr int DIN  = 128;
constexpr int DOUT = 128;
constexpr float EPS_SCALE = 1e-7f;

typedef __attribute__((ext_vector_type(8))) short bf16x8;
typedef __attribute__((ext_vector_type(4))) float f32x4;

__device__ __forceinline__ float lrelu(float x) { return fmaxf(x, 0.01f * x); }

__device__ __forceinline__ unsigned short f2bf(float x) {
    unsigned u = __float_as_uint(x);
    unsigned r = (u + 0x7FFFu + ((u >> 16) & 1u)) >> 16;   // RNE
    return (unsigned short)r;
}
__device__ __forceinline__ float bf2f(unsigned short h) {
    return __uint_as_float(((unsigned)h) << 16);
}

// ---------------------------------------------------------------------------
// 1) Fused prep: hist(dst) | feat fp32->bf16 | pack W frags + combined bias.
// ---------------------------------------------------------------------------
__global__ __launch_bounds__(256) void prep_kernel(
    const int* __restrict__ dst, int* __restrict__ hist, int E, int eb,
    const float* __restrict__ feat, unsigned short* __restrict__ featbf,
    int total8, int cb,
    const float* __restrict__ Wself, const float* __restrict__ Wneigh,
    const float* __restrict__ b_self, const float* __restrict__ b_neigh,
    const float* __restrict__ bias,
    unsigned short* __restrict__ bfrag, float* __restrict__ bb)
{
    int b = blockIdx.x;
    int tid = threadIdx.x;
    if (b < eb) {
        int e = b * 256 + tid;
        if (e < E) atomicAdd(&hist[dst[e]], 1);
    } else if (b < eb + cb) {
        int i = (b - eb) * 256 + tid;          // handles 8 floats
        if (i < total8) {
            float4 v0 = *(const float4*)(feat + (size_t)i * 8);
            float4 v1 = *(const float4*)(feat + (size_t)i * 8 + 4);
            bf16x8 o;
            o[0] = (short)f2bf(v0.x); o[1] = (short)f2bf(v0.y);
            o[2] = (short)f2bf(v0.z); o[3] = (short)f2bf(v0.w);
            o[4] = (short)f2bf(v1.x); o[5] = (short)f2bf(v1.y);
            o[6] = (short)f2bf(v1.z); o[7] = (short)f2bf(v1.w);
            *(bf16x8*)(featbf + (size_t)i * 8) = o;
        }
    } else {
        int idx = (b - eb - cb) * 256 + tid;   // 0..32767
        if (idx < 32768) {
            int j = idx & 7;
            int l = (idx >> 3) & 63;
            int f = (idx >> 9) & 7;
            int s = (idx >> 12) & 7;
            int k = s * 32 + ((l >> 4) << 3) + j;
            int c = f * 16 + (l & 15);
            float v = (k < 128) ? Wself[c * 128 + k] : Wneigh[c * 128 + (k - 128)];
            bfrag[idx] = f2bf(v);
        }
        if (idx < 128) bb[idx] = b_self[idx] + b_neigh[idx] + bias[idx];
    }
}

// ---------------------------------------------------------------------------
// 2a) Per-block partial sums over 1024-elem chunks
// ---------------------------------------------------------------------------
__global__ __launch_bounds__(256) void scan_part1(
    const int* __restrict__ hist, int* __restrict__ bsum, int N)
{
    __shared__ int wsum[4];
    int tid = threadIdx.x, wave = tid >> 6, lane = tid & 63;
    int idx = blockIdx.x * 1024 + tid * 4;
    int4 h = make_int4(0, 0, 0, 0);
    if (idx < N) h = *(const int4*)(hist + idx);
    int s = h.x + h.y + h.z + h.w;
#pragma unroll
    for (int off = 1; off < 64; off <<= 1) s += __shfl_xor(s, off, 64);
    if (lane == 0) wsum[wave] = s;
    __syncthreads();
    if (tid == 0) bsum[blockIdx.x] = wsum[0] + wsum[1] + wsum[2] + wsum[3];
}

// ---------------------------------------------------------------------------
// 2b) Exclusive scan of <=64 block partials; rowptr[N] = E
// ---------------------------------------------------------------------------
__global__ __launch_bounds__(64) void scan_part2(
    const int* __restrict__ bsum, int* __restrict__ bbase, int nb,
    int* __restrict__ rowptr, int N, int E)
{
    int lane = threadIdx.x;
    int x = (lane < nb) ? bsum[lane] : 0;
    int orig = x;
#pragma unroll
    for (int off = 1; off < 64; off <<= 1) {
        int v = __shfl_up(x, off, 64);
        if (lane >= off) x += v;
    }
    if (lane < nb) bbase[lane] = x - orig;
    if (lane == 0) rowptr[N] = E;
}

// ---------------------------------------------------------------------------
// 2c) In-block exclusive scan + block base -> rowptr[0..N-1]
// ---------------------------------------------------------------------------
__global__ __launch_bounds__(256) void scan_part3(
    const int* __restrict__ hist, const int* __restrict__ bbase,
    int* __restrict__ rowptr, int N)
{
    __shared__ int wsum[4];
    int tid = threadIdx.x, wave = tid >> 6, lane = tid & 63;
    int idx = blockIdx.x * 1024 + tid * 4;
    int4 h = make_int4(0, 0, 0, 0);
    if (idx < N) h = *(const int4*)(hist + idx);
    int s = h.x + h.y + h.z + h.w;
    int x = s;
#pragma unroll
    for (int off = 1; off < 64; off <<= 1) {
        int v = __shfl_up(x, off, 64);
        if (lane >= off) x += v;
    }
    if (lane == 63) wsum[wave] = x;
    __syncthreads();
    int wb = 0;
#pragma unroll
    for (int w = 0; w < 4; ++w) if (w < wave) wb += wsum[w];
    int base = bbase[blockIdx.x] + wb + (x - s);
    if (idx < N) {
        rowptr[idx + 0] = base;
        rowptr[idx + 1] = base + h.x;
        rowptr[idx + 2] = base + h.x + h.y;
        rowptr[idx + 3] = base + h.x + h.y + h.z;
    }
}

// ---------------------------------------------------------------------------
// 3) Scatter: compute per-edge spatial coeff + pack src id, in CSR order.
// ---------------------------------------------------------------------------
__global__ __launch_bounds__(256) void scatter_kernel(
    const int* __restrict__ dst, const int* __restrict__ src,
    const float* __restrict__ pos,
    const int* __restrict__ rowptr, int* __restrict__ cur,
    float4* __restrict__ ecoef, int E)
{
    int e = blockIdx.x * blockDim.x + threadIdx.x;
    if (e < E) {
        int d = dst[e];
        int s = src[e];
        float r0 = pos[d * 3 + 0] - pos[s * 3 + 0];
        float r1 = pos[d * 3 + 1] - pos[s * 3 + 1];
        float r2 = pos[d * 3 + 2] - pos[s * 3 + 2];
        float inv = 1.0f / (sqrtf(r0 * r0 + r1 * r1 + r2 * r2) + EPS_SCALE);
        int p = atomicAdd(&cur[d], 1);
        ecoef[rowptr[d] + p] = make_float4((r0 + 1.0f) * inv, (r1 + 1.0f) * inv,
                                           (r2 + 1.0f) * inv, __int_as_float(s));
    }
}

// ---------------------------------------------------------------------------
// 4) Gather: persistent waves, TWO nodes per wave (one per 32-lane half).
//    Within a half: e2 = (lane>>4)&1 gives 2-way edge parallelism, 2x
//    unrolled -> 4 chains/node, 8 chains/wave (proven MLP depth).
//    sl = lane&15 owns dims sl*8..sl*8+7. Reduce = single xor(16) per acc
//    (halves fully independent). Store lanes: e2==0 (32 of 64 active).
// ---------------------------------------------------------------------------
#define EDGE_FMA(QC, F)                                                          \
    do {                                                                         \
        a0 = fmaf(lrelu(fmaf(QC.x, w0.x, fmaf(QC.y, w0.y, fmaf(QC.z, w0.z, b0.x)))), \
                  bf2f((unsigned short)F[0]), a0);                               \
        a1 = fmaf(lrelu(fmaf(QC.x, w0.w, fmaf(QC.y, w1.x, fmaf(QC.z, w1.y, b0.y)))), \
                  bf2f((unsigned short)F[1]), a1);                               \
        a2 = fmaf(lrelu(fmaf(QC.x, w1.z, fmaf(QC.y, w1.w, fmaf(QC.z, w2.x, b0.z)))), \
                  bf2f((unsigned short)F[2]), a2);                               \
        a3 = fmaf(lrelu(fmaf(QC.x, w2.y, fmaf(QC.y, w2.z, fmaf(QC.z, w2.w, b0.w)))), \
                  bf2f((unsigned short)F[3]), a3);                               \
        a4 = fmaf(lrelu(fmaf(QC.x, w3.x, fmaf(QC.y, w3.y, fmaf(QC.z, w3.z, b1.x)))), \
                  bf2f((unsigned short)F[4]), a4);                               \
        a5 = fmaf(lrelu(fmaf(QC.x, w3.w, fmaf(QC.y, w4.x, fmaf(QC.z, w4.y, b1.y)))), \
                  bf2f((unsigned short)F[5]), a5);                               \
        a6 = fmaf(lrelu(fmaf(QC.x, w4.z, fmaf(QC.y, w4.w, fmaf(QC.z, w5.x, b1.z)))), \
                  bf2f((unsigned short)F[6]), a6);                               \
        a7 = fmaf(lrelu(fmaf(QC.x, w5.y, fmaf(QC.y, w5.z, fmaf(QC.z, w5.w, b1.w)))), \
                  bf2f((unsigned short)F[7]), a7);                               \
    } while (0)

__global__ __launch_bounds__(256) void gather_kernel(
    const unsigned short* __restrict__ featbf,
    const float4* __restrict__ ecoef,
    const int*   __restrict__ rowptr,
    const float* __restrict__ Wsp,   // [128][3]
    const float* __restrict__ bsp,   // [128]
    unsigned short* __restrict__ hmbf,  // [N][128]
    int N, int nwaves)
{
    int gw   = (blockIdx.x * 256 + threadIdx.x) >> 6;
    int lane = threadIdx.x & 63;
    int half = lane >> 5;          // which node of the pair
    int e2   = (lane >> 4) & 1;    // edge slot within the node
    int sl   = lane & 15;
    int d    = sl * 8;

    const float4* wp = (const float4*)(Wsp + d * 3);
    float4 w0 = wp[0], w1 = wp[1], w2 = wp[2];
    float4 w3 = wp[3], w4 = wp[4], w5 = wp[5];
    float4 b0 = *(const float4*)(bsp + d);
    float4 b1 = *(const float4*)(bsp + d + 4);

    const unsigned short* fb = featbf + d;
    int stride = nwaves * 2;

    for (int vp = gw * 2; vp < N; vp += stride) {
        int v = vp + half;
        int start = 0, end = 0;
        if (v < N) { start = rowptr[v]; end = rowptr[v + 1]; }

        float a0 = 0.f, a1 = 0.f, a2 = 0.f, a3 = 0.f;
        float a4 = 0.f, a5 = 0.f, a6 = 0.f, a7 = 0.f;

        int i = start + e2;
        // Pairs: edges i and i+2, all loads issued before compute.
        for (; i + 2 < end; i += 4) {
            float4 qcA = ecoef[i];
            float4 qcB = ecoef[i + 2];
            bf16x8 fA = *(const bf16x8*)(fb + (size_t)__float_as_int(qcA.w) * DIN);
            bf16x8 fB = *(const bf16x8*)(fb + (size_t)__float_as_int(qcB.w) * DIN);
            EDGE_FMA(qcA, fA);
            EDGE_FMA(qcB, fB);
        }
        if (i < end) {
            float4 qcA = ecoef[i];
            bf16x8 fA = *(const bf16x8*)(fb + (size_t)__float_as_int(qcA.w) * DIN);
            EDGE_FMA(qcA, fA);
        }

        // combine the two edge slots (within the 32-lane half)
        a0 += __shfl_xor(a0, 16);
        a1 += __shfl_xor(a1, 16);
        a2 += __shfl_xor(a2, 16);
        a3 += __shfl_xor(a3, 16);
        a4 += __shfl_xor(a4, 16);
        a5 += __shfl_xor(a5, 16);
        a6 += __shfl_xor(a6, 16);
        a7 += __shfl_xor(a7, 16);

        if (e2 == 0 && v < N) {
            float invd = 1.0f / fmaxf((float)(end - start), 1.0f);
            bf16x8 o;
            o[0] = (short)f2bf(a0 * invd); o[1] = (short)f2bf(a1 * invd);
            o[2] = (short)f2bf(a2 * invd); o[3] = (short)f2bf(a3 * invd);
            o[4] = (short)f2bf(a4 * invd); o[5] = (short)f2bf(a5 * invd);
            o[6] = (short)f2bf(a6 * invd); o[7] = (short)f2bf(a7 * invd);
            *(bf16x8*)(hmbf + (size_t)v * DIN + d) = o;
        }
    }
}

// ---------------------------------------------------------------------------
// 5) Node GEMM via MFMA: out = lrelu([featbf | hmbf] @ Wc^T + bb)
// ---------------------------------------------------------------------------
__global__ __launch_bounds__(256) void node_mfma_kernel(
    const unsigned short* __restrict__ featbf,
    const unsigned short* __restrict__ hmbf,
    const unsigned short* __restrict__ bfrag,
    const float* __restrict__ bb,
    float* __restrict__ out, int N)
{
    int wave = threadIdx.x >> 6;
    int lane = threadIdx.x & 63;
    int r0   = blockIdx.x * 64 + wave * 16;
    int row  = r0 + (lane & 15);
    bool rowok = row < N;
    int kb = (lane >> 4) << 3;

    f32x4 acc[8];
#pragma unroll
    for (int f = 0; f < 8; ++f) acc[f] = (f32x4)0.0f;

#pragma unroll
    for (int s = 0; s < 8; ++s) {
        bf16x8 a = (bf16x8)(short)0;
        if (rowok) {
            const unsigned short* base =
                (s < 4 ? featbf : hmbf) + (size_t)row * DIN + (s & 3) * 32 + kb;
            a = *(const bf16x8*)base;
        }
#pragma unroll
        for (int f = 0; f < 8; ++f) {
            bf16x8 b = *(const bf16x8*)(bfrag + ((((s * 8 + f) * 64) + lane) * 8));
            acc[f] = __builtin_amdgcn_mfma_f32_16x16x32_bf16(a, b, acc[f], 0, 0, 0);
        }
    }

    int crow = r0 + ((lane >> 4) << 2);
    int col  = lane & 15;
#pragma unroll
    for (int f = 0; f < 8; ++f) {
        int c = f * 16 + col;
        float bbv = bb[c];
#pragma unroll
        for (int r = 0; r < 4; ++r) {
            int rr = crow + r;
            if (rr < N) out[(size_t)rr * DOUT + c] = lrelu(acc[f][r] + bbv);
        }
    }
}

// ---------------------------------------------------------------------------
extern "C" void kernel_launch(void* const* d_in, const int* in_sizes, int n_in,
                              void* d_out, int out_size, void* d_ws, size_t ws_size,
                              hipStream_t stream)
{
    const float* feat    = (const float*)d_in[0];
    const float* pos     = (const float*)d_in[1];
    const int*   src     = (const int*)  d_in[2];
    const int*   dst     = (const int*)  d_in[3];
    const float* Wsp     = (const float*)d_in[4];
    const float* bsp     = (const float*)d_in[5];
    const float* Wneigh  = (const float*)d_in[6];
    const float* b_neigh = (const float*)d_in[7];
    const float* Wself   = (const float*)d_in[8];
    const float* b_self  = (const float*)d_in[9];
    const float* bias    = (const float*)d_in[10];

    int N = in_sizes[0] / DIN;
    int E = in_sizes[2];
    int nb = (N + 1023) / 1024;   // scan blocks (49 for N=50000; <= 64)

    // Workspace layout (all 16B aligned):
    // featbf [N*128 u16] | hmbf [N*128 u16] | ecoef [E f4] | bfrag [32768 u16]
    // | bb [128 f32] | hist [N] | cur [N] | rowptr [N+4] | bsum [64] | bbase [64]
    char* p = (char*)d_ws;
    unsigned short* featbf = (unsigned short*)p; p += (size_t)N * DIN * 2;
    unsigned short* hmbf   = (unsigned short*)p; p += (size_t)N * DIN * 2;
    float4* ecoef          = (float4*)p;         p += (size_t)E * 16;
    unsigned short* bfrag  = (unsigned short*)p; p += 32768 * 2;
    float* bb              = (float*)p;          p += 128 * 4;
    int* hist              = (int*)p;            p += (size_t)N * 4;
    int* cur               = (int*)p;            p += (size_t)N * 4;
    int* rowptr            = (int*)p;            p += (size_t)(N + 4) * 4;
    int* bsum              = (int*)p;            p += 64 * 4;
    int* bbase             = (int*)p;

    // zero hist + cur (adjacent)
    hipMemsetAsync(hist, 0, (size_t)2 * N * sizeof(int), stream);

    int eb = (E + 255) / 256;            // hist blocks
    int cb = (N * 16 + 255) / 256;       // convert blocks (N*128/8 threads)
    int pb = 129;                        // pack blocks
    prep_kernel<<<eb + cb + pb, 256, 0, stream>>>(
        dst, hist, E, eb, feat, featbf, N * 16, cb,
        Wself, Wneigh, b_self, b_neigh, bias, bfrag, bb);

    scan_part1<<<nb, 256, 0, stream>>>(hist, bsum, N);
    scan_part2<<<1, 64, 0, stream>>>(bsum, bbase, nb, rowptr, N, E);
    scan_part3<<<nb, 256, 0, stream>>>(hist, bbase, rowptr, N);

    scatter_kernel<<<eb, 256, 0, stream>>>(dst, src, pos, rowptr, cur, ecoef, E);

    int gblocks = 2048;
    gather_kernel<<<gblocks, 256, 0, stream>>>(featbf, ecoef, rowptr, Wsp, bsp,
                                               hmbf, N, gblocks * 4);

    node_mfma_kernel<<<(N + 63) / 64, 256, 0, stream>>>(featbf, hmbf, bfrag, bb,
                                                        (float*)d_out, N);
}